// Round 3
// baseline (108.819 us; speedup 1.0000x reference)
//
#include <hip/hip_runtime.h>
#include <hip/hip_bf16.h>

// Problem constants (from reference)
#define B_    64
#define T_    500
#define DIN   1024
#define DOUT  128
#define EPSV  1e-8f
#define BM    32          // t-rows per workgroup tile
#define NTILE 16          // ceil(500/32)
#define NKC   2           // k-chunks (512 each)
#define KCL   512         // k-chunk length

typedef __attribute__((ext_vector_type(8))) short bf16x8;  // MFMA A/B frag (8 bf16)
typedef __attribute__((ext_vector_type(4))) float f32x4;   // MFMA C/D frag

// Workspace layout (byte offsets)
//   wT    : bf16 [DOUT][DIN]             @ 0        (262144 B)
//   wtab  : f32  [T_][DOUT]              @ 262144   (256000 B)  c[t][d]=1-beta[d]^(T-t)
//   scale : f32  [DOUT]                  @ 518144   (512 B)     1/(T*(norm+eps))
//   part  : f32  [B_][NTILE][NKC][DOUT]  @ 518656   (1048576 B)
#define OFF_WTAB  262144
#define OFF_SCALE 518144
#define OFF_PART  518656

__device__ inline short f2bf(float f) {
    __hip_bfloat16 h = __float2bfloat16(f);
    return __builtin_bit_cast(short, h);
}

// ---------------- prep: transpose/convert w, norm->scale, weight table ----------------
__global__ __launch_bounds__(256) void prep_kernel(
    const float* __restrict__ w, const float* __restrict__ beta,
    __hip_bfloat16* __restrict__ wT, float* __restrict__ wtab,
    float* __restrict__ scale)
{
    int bid = blockIdx.x, tid = threadIdx.x;
    if (bid < 512) {
        int i = bid * 256 + tid;
        int d = i >> 10, k = i & 1023;
        wT[(size_t)d * DIN + k] = __float2bfloat16(w[(size_t)k * DOUT + d]);
    } else if (bid < 640) {
        int d = bid - 512;
        __shared__ float red[256];
        float s = 0.f;
        for (int c = tid; c < DIN; c += 256) {
            float v = w[(size_t)c * DOUT + d];
            s += v * v;
        }
        red[tid] = s;
        __syncthreads();
        for (int off = 128; off > 0; off >>= 1) {
            if (tid < off) red[tid] += red[tid + off];
            __syncthreads();
        }
        if (tid == 0) scale[d] = 1.f / ((red[0] + EPSV) * (float)T_);
    } else {
        int i = (bid - 640) * 256 + tid;
        if (i < T_ * DOUT) {
            int t = i >> 7, d = i & 127;
            wtab[i] = 1.f - powf(beta[d], (float)(T_ - t));
        }
    }
}

// ---------------- main: fused GEMM + weighted time-reduction ----------------
// grid: 2048 blocks = 64 b x 16 t-tiles x 2 k-chunks; 4 waves/block, wave w
// owns cols [w*32, w*32+32) of its 32-row tile over 512 k.
// Register double-buffered: load step i+1 while MFMA-ing step i.
__global__ __launch_bounds__(256, 4) void gemm_kernel(
    const float* __restrict__ x, const __hip_bfloat16* __restrict__ wT,
    const float* __restrict__ wtab, float* __restrict__ partials)
{
    int wg   = blockIdx.x;
    int kc   = wg & 1;
    int tile = (wg >> 1) & 15;
    int b    = wg >> 5;
    int t0   = tile * BM;
    int wave = threadIdx.x >> 6;
    int lane = threadIdx.x & 63;
    int arow = lane & 15;
    int kblk = lane >> 4;
    int kbase = kc * KCL;

    const float* xb = x + (size_t)b * T_ * DIN;

    // row addresses (clamp t>=500; weight is 0 there so garbage*0 = 0, values finite)
    int tr0 = t0 + arow;       int tc0 = tr0 < T_ ? tr0 : T_ - 1;
    int tr1 = t0 + 16 + arow;  int tc1 = tr1 < T_ ? tr1 : T_ - 1;

    const float* pa0 = xb + (size_t)tc0 * DIN + kblk * 8 + kbase;
    const float* pa1 = xb + (size_t)tc1 * DIN + kblk * 8 + kbase;

    int c0 = wave * 32;
    const __hip_bfloat16* pb0 = wT + (size_t)(c0 + arow) * DIN + kblk * 8 + kbase;
    const __hip_bfloat16* pb1 = wT + (size_t)(c0 + 16 + arow) * DIN + kblk * 8 + kbase;

    f32x4 acc00 = {0.f,0.f,0.f,0.f}, acc01 = {0.f,0.f,0.f,0.f};
    f32x4 acc10 = {0.f,0.f,0.f,0.f}, acc11 = {0.f,0.f,0.f,0.f};

    // register double-buffer: two step-reg sets, all indices compile-time
#define DECL_STEP(S) float4 S##a0l, S##a0h, S##a1l, S##a1h; bf16x8 S##b0, S##b1;
#define LOAD_STEP(S, K) \
    S##a0l = *reinterpret_cast<const float4*>(pa0 + (K));      \
    S##a0h = *reinterpret_cast<const float4*>(pa0 + (K) + 4);  \
    S##a1l = *reinterpret_cast<const float4*>(pa1 + (K));      \
    S##a1h = *reinterpret_cast<const float4*>(pa1 + (K) + 4);  \
    S##b0  = *reinterpret_cast<const bf16x8*>(pb0 + (K));      \
    S##b1  = *reinterpret_cast<const bf16x8*>(pb1 + (K));
#define COMPUTE_STEP(S) {                                                     \
    bf16x8 af0, af1;                                                          \
    af0[0]=f2bf(S##a0l.x); af0[1]=f2bf(S##a0l.y); af0[2]=f2bf(S##a0l.z); af0[3]=f2bf(S##a0l.w); \
    af0[4]=f2bf(S##a0h.x); af0[5]=f2bf(S##a0h.y); af0[6]=f2bf(S##a0h.z); af0[7]=f2bf(S##a0h.w); \
    af1[0]=f2bf(S##a1l.x); af1[1]=f2bf(S##a1l.y); af1[2]=f2bf(S##a1l.z); af1[3]=f2bf(S##a1l.w); \
    af1[4]=f2bf(S##a1h.x); af1[5]=f2bf(S##a1h.y); af1[6]=f2bf(S##a1h.z); af1[7]=f2bf(S##a1h.w); \
    acc00 = __builtin_amdgcn_mfma_f32_16x16x32_bf16(af0, S##b0, acc00, 0, 0, 0); \
    acc01 = __builtin_amdgcn_mfma_f32_16x16x32_bf16(af0, S##b1, acc01, 0, 0, 0); \
    acc10 = __builtin_amdgcn_mfma_f32_16x16x32_bf16(af1, S##b0, acc10, 0, 0, 0); \
    acc11 = __builtin_amdgcn_mfma_f32_16x16x32_bf16(af1, S##b1, acc11, 0, 0, 0); }

    DECL_STEP(s0_) DECL_STEP(s1_)

    LOAD_STEP(s0_, 0)
#pragma unroll
    for (int i = 0; i < 8; ++i) {
        LOAD_STEP(s1_, 64 * i + 32)
        COMPUTE_STEP(s0_)
        if (i < 7) { LOAD_STEP(s0_, 64 * i + 64) }
        COMPUTE_STEP(s1_)
    }
#undef DECL_STEP
#undef LOAD_STEP
#undef COMPUTE_STEP

    // Epilogue: weighted reduction over the 32 tile rows.
    // Lane holds rows rf*16 + kblk*4 + r (r=0..3), col c0 + cf*16 + arow.
    int d0 = c0 + arow;
    int d1 = c0 + 16 + arow;
    float s0 = 0.f, s1 = 0.f;
#pragma unroll
    for (int r = 0; r < 4; ++r) {
        int ta = t0 + kblk * 4 + r;   // rf = 0
        int tb = ta + 16;             // rf = 1
        float wa0 = (ta < T_) ? wtab[ta * DOUT + d0] : 0.f;
        float wb0 = (tb < T_) ? wtab[tb * DOUT + d0] : 0.f;
        float wa1 = (ta < T_) ? wtab[ta * DOUT + d1] : 0.f;
        float wb1 = (tb < T_) ? wtab[tb * DOUT + d1] : 0.f;
        s0 += wa0 * acc00[r] + wb0 * acc10[r];
        s1 += wa1 * acc01[r] + wb1 * acc11[r];
    }
    s0 += __shfl_xor(s0, 16); s0 += __shfl_xor(s0, 32);
    s1 += __shfl_xor(s1, 16); s1 += __shfl_xor(s1, 32);

    if (kblk == 0) {
        float* p = partials + (((size_t)b * NTILE + tile) * NKC + kc) * DOUT;
        p[d0] = s0;
        p[d1] = s1;
    }
}

// ---------------- finalize: sum partials, scale, bias ----------------
__global__ __launch_bounds__(256) void finalize_kernel(
    const float* __restrict__ partials, const float* __restrict__ scale,
    const float* __restrict__ bias, float* __restrict__ out)
{
    int i = blockIdx.x * 256 + threadIdx.x;  // 8192 = B_*DOUT
    int b = i >> 7, d = i & 127;
    float s = 0.f;
#pragma unroll
    for (int p = 0; p < NTILE * NKC; ++p)
        s += partials[((size_t)b * NTILE * NKC + p) * DOUT + d];
    out[i] = s * scale[d] - bias[d];
}

extern "C" void kernel_launch(void* const* d_in, const int* in_sizes, int n_in,
                              void* d_out, int out_size, void* d_ws, size_t ws_size,
                              hipStream_t stream) {
    const float* x    = (const float*)d_in[0];  // [64][500][1024]
    const float* w    = (const float*)d_in[1];  // [1024][128]
    const float* beta = (const float*)d_in[2];  // [128]
    const float* bias = (const float*)d_in[3];  // [128]
    float* out = (float*)d_out;                 // [64][128] fp32

    char* ws = (char*)d_ws;
    __hip_bfloat16* wT = (__hip_bfloat16*)(ws);
    float* wtab     = (float*)(ws + OFF_WTAB);
    float* scale    = (float*)(ws + OFF_SCALE);
    float* partials = (float*)(ws + OFF_PART);

    prep_kernel<<<890, 256, 0, stream>>>(w, beta, wT, wtab, scale);
    gemm_kernel<<<B_ * NTILE * NKC, 256, 0, stream>>>(x, wT, wtab, partials);
    finalize_kernel<<<(B_ * DOUT) / 256, 256, 0, stream>>>(partials, scale, bias, out);
}

// Round 4
// 40.904 us; speedup vs baseline: 2.6604x; 2.6604x over previous
//
#include <hip/hip_runtime.h>
#include <hip/hip_bf16.h>

// Problem constants
#define B_    64
#define T_    500
#define DIN   1024
#define DOUT  128
#define EPSV  1e-8f
#define BM    128          // t-rows per block tile
#define BK    64           // k per LDS stage
#define NKT   (DIN / BK)   // 16
#define TILES 4            // ceil(500/128)

typedef __attribute__((ext_vector_type(8))) short bf16x8;  // MFMA A/B frag
typedef __attribute__((ext_vector_type(4))) float f32x4;   // MFMA C/D frag

// Workspace layout (byte offsets)
//   wT    : bf16 [DOUT][DIN]              @ 0        (262144 B)
//   wtab  : f32  [T_][DOUT]               @ 262144   (256000 B)  c[t][d]=1-beta[d]^(T-t)
//   scale : f32  [DOUT]                   @ 518144   (512 B)
//   part  : f32  [B_][TILES][2][DOUT]     @ 518656   (262144 B)
#define OFF_WTAB  262144
#define OFF_SCALE 518144
#define OFF_PART  518656

__device__ inline short f2bf(float f) {
    __hip_bfloat16 h = __float2bfloat16(f);
    return __builtin_bit_cast(short, h);
}

// ---------------- prep: transpose/convert w, norm->scale, weight table ----------------
__global__ __launch_bounds__(256) void prep_kernel(
    const float* __restrict__ w, const float* __restrict__ beta,
    __hip_bfloat16* __restrict__ wT, float* __restrict__ wtab,
    float* __restrict__ scale)
{
    int bid = blockIdx.x, tid = threadIdx.x;
    if (bid < 512) {
        int i = bid * 256 + tid;
        int d = i >> 10, k = i & 1023;
        wT[(size_t)d * DIN + k] = __float2bfloat16(w[(size_t)k * DOUT + d]);
    } else if (bid < 640) {
        int d = bid - 512;
        __shared__ float red[256];
        float s = 0.f;
        for (int c = tid; c < DIN; c += 256) {
            float v = w[(size_t)c * DOUT + d];
            s += v * v;
        }
        red[tid] = s;
        __syncthreads();
        for (int off = 128; off > 0; off >>= 1) {
            if (tid < off) red[tid] += red[tid + off];
            __syncthreads();
        }
        if (tid == 0) scale[d] = 1.f / ((red[0] + EPSV) * (float)T_);
    } else {
        int i = (bid - 640) * 256 + tid;
        if (i < T_ * DOUT) {
            int t = i >> 7, d = i & 127;
            wtab[i] = 1.f - powf(beta[d], (float)(T_ - t));
        }
    }
}

// ---------------- main: LDS-staged GEMM + fused weighted time-reduction ----------------
// 256 blocks = 64 b x 4 t-tiles; 512 threads = 8 waves in 2x4 (wr x wc) layout.
// Wave owns 64 rows x 32 cols. LDS: double-buffered A[128][64]bf16 + B[128][64]bf16,
// XOR-swizzled (byte ^= (row&7)<<4) to kill the 16-way bank conflict of 128B-stride rows.
__global__ __launch_bounds__(512, 2) void gemm_kernel(
    const float* __restrict__ x, const __hip_bfloat16* __restrict__ wT,
    const float* __restrict__ wtab, float* __restrict__ partials)
{
    __shared__ __align__(16) char smem[2 * 32768];  // buf: A @0 (16KB), B @16KB

    const int wg   = blockIdx.x;
    const int tile = wg & 3;
    const int b    = wg >> 2;
    const int t0   = tile * BM;
    const int tid  = threadIdx.x;
    const int wid  = tid >> 6;
    const int lane = tid & 63;
    const int arow = lane & 15;
    const int kblk = lane >> 4;
    const int wr   = wid >> 2;   // 0..1  (row group of 64)
    const int wc   = wid & 3;    // 0..3  (col group of 32)

    const float* xb = x + (size_t)b * T_ * DIN;

    // ---- staging geometry (loop-invariant) ----
    // A: 4 passes; pass p covers rows p*32..p*32+31; 16 threads x float4 per row.
    const int sr = tid >> 4;     // 0..31 (row within pass)
    const int sc = tid & 15;     // float4 index within row
    const float* ag[4];
    int awoff[4];
#pragma unroll
    for (int p = 0; p < 4; ++p) {
        int row  = p * 32 + sr;
        int trow = t0 + row; if (trow >= T_) trow = T_ - 1;  // clamp; weight=0 kills it
        ag[p] = xb + (size_t)trow * DIN + sc * 4;
        awoff[p] = (row * 128 + sc * 8) ^ ((row & 7) << 4);
    }
    // B: col = tid>>2 (0..127); 2 chunks of 16B per thread
    const int bcol = tid >> 2;
    const int bch0 = (tid & 3) * 2;
    const __hip_bfloat16* bg0 = wT + (size_t)bcol * DIN + bch0 * 8;
    const __hip_bfloat16* bg1 = bg0 + 8;
    const int bwoff0 = (bcol * 128 + bch0 * 16)        ^ ((bcol & 7) << 4);
    const int bwoff1 = (bcol * 128 + (bch0 + 1) * 16)  ^ ((bcol & 7) << 4);

    // fragment read offsets (within A/B region), loop-invariant
    int aro[4][2], bro[2][2];
#pragma unroll
    for (int fm = 0; fm < 4; ++fm)
#pragma unroll
        for (int kk = 0; kk < 2; ++kk) {
            int row = wr * 64 + fm * 16 + arow;
            aro[fm][kk] = (row * 128 + kk * 64 + kblk * 16) ^ ((row & 7) << 4);
        }
#pragma unroll
    for (int fn = 0; fn < 2; ++fn)
#pragma unroll
        for (int kk = 0; kk < 2; ++kk) {
            int col = wc * 32 + fn * 16 + arow;
            bro[fn][kk] = (col * 128 + kk * 64 + kblk * 16) ^ ((col & 7) << 4);
        }

    f32x4 acc[4][2] = {};

    // ---- prologue: stage kt=0 into buf 0 ----
    {
        char* Ab = smem;
        char* Bb = smem + 16384;
#pragma unroll
        for (int p = 0; p < 4; ++p) {
            float4 v = *reinterpret_cast<const float4*>(ag[p]);
            short4 h; h.x = f2bf(v.x); h.y = f2bf(v.y); h.z = f2bf(v.z); h.w = f2bf(v.w);
            *reinterpret_cast<short4*>(Ab + awoff[p]) = h;
        }
        *reinterpret_cast<bf16x8*>(Bb + bwoff0) = *reinterpret_cast<const bf16x8*>(bg0);
        *reinterpret_cast<bf16x8*>(Bb + bwoff1) = *reinterpret_cast<const bf16x8*>(bg1);
    }
    __syncthreads();

    // ---- main loop: issue next-tile global loads, compute current, write next ----
    for (int kt = 0; kt < NKT; ++kt) {
        const int cur = kt & 1;
        char* Acur = smem + cur * 32768;
        char* Bcur = Acur + 16384;
        char* Anxt = smem + (cur ^ 1) * 32768;
        char* Bnxt = Anxt + 16384;

        float4 av[4]; bf16x8 bv0, bv1;
        if (kt < NKT - 1) {
            const int kb = (kt + 1) * BK;
#pragma unroll
            for (int p = 0; p < 4; ++p)
                av[p] = *reinterpret_cast<const float4*>(ag[p] + kb);
            bv0 = *reinterpret_cast<const bf16x8*>(bg0 + kb);
            bv1 = *reinterpret_cast<const bf16x8*>(bg1 + kb);
        }

        bf16x8 af[4][2], bf[2][2];
#pragma unroll
        for (int fm = 0; fm < 4; ++fm)
#pragma unroll
            for (int kk = 0; kk < 2; ++kk)
                af[fm][kk] = *reinterpret_cast<const bf16x8*>(Acur + aro[fm][kk]);
#pragma unroll
        for (int fn = 0; fn < 2; ++fn)
#pragma unroll
            for (int kk = 0; kk < 2; ++kk)
                bf[fn][kk] = *reinterpret_cast<const bf16x8*>(Bcur + bro[fn][kk]);

#pragma unroll
        for (int kk = 0; kk < 2; ++kk)
#pragma unroll
            for (int fm = 0; fm < 4; ++fm)
#pragma unroll
                for (int fn = 0; fn < 2; ++fn)
                    acc[fm][fn] = __builtin_amdgcn_mfma_f32_16x16x32_bf16(
                        af[fm][kk], bf[fn][kk], acc[fm][fn], 0, 0, 0);

        if (kt < NKT - 1) {
#pragma unroll
            for (int p = 0; p < 4; ++p) {
                short4 h; h.x = f2bf(av[p].x); h.y = f2bf(av[p].y);
                h.z = f2bf(av[p].z); h.w = f2bf(av[p].w);
                *reinterpret_cast<short4*>(Anxt + awoff[p]) = h;
            }
            *reinterpret_cast<bf16x8*>(Bnxt + bwoff0) = bv0;
            *reinterpret_cast<bf16x8*>(Bnxt + bwoff1) = bv1;
        }
        __syncthreads();
    }

    // ---- epilogue: weighted reduction over rows within the wave's 64-row strip ----
    // C frag: col = lane&15, row = (lane>>4)*4 + r  [verified mapping]
    const int col0 = wc * 32 + arow;
    const int col1 = col0 + 16;
    float s0 = 0.f, s1 = 0.f;
#pragma unroll
    for (int fm = 0; fm < 4; ++fm) {
#pragma unroll
        for (int r = 0; r < 4; ++r) {
            int t = t0 + wr * 64 + fm * 16 + kblk * 4 + r;
            if (t < T_) {
                s0 += wtab[t * DOUT + col0] * acc[fm][0][r];
                s1 += wtab[t * DOUT + col1] * acc[fm][1][r];
            }
        }
    }
    s0 += __shfl_xor(s0, 16); s0 += __shfl_xor(s0, 32);
    s1 += __shfl_xor(s1, 16); s1 += __shfl_xor(s1, 32);

    if (kblk == 0) {
        float* p = partials + (((size_t)b * TILES + tile) * 2 + wr) * DOUT;
        p[col0] = s0;
        p[col1] = s1;
    }
}

// ---------------- finalize: sum partials, scale, bias ----------------
__global__ __launch_bounds__(256) void finalize_kernel(
    const float* __restrict__ partials, const float* __restrict__ scale,
    const float* __restrict__ bias, float* __restrict__ out)
{
    int i = blockIdx.x * 256 + threadIdx.x;  // 8192 = B_*DOUT
    int b = i >> 7, d = i & 127;
    float s = 0.f;
#pragma unroll
    for (int p = 0; p < TILES * 2; ++p)
        s += partials[((size_t)b * TILES * 2 + p) * DOUT + d];
    out[i] = s * scale[d] - bias[d];
}

extern "C" void kernel_launch(void* const* d_in, const int* in_sizes, int n_in,
                              void* d_out, int out_size, void* d_ws, size_t ws_size,
                              hipStream_t stream) {
    const float* x    = (const float*)d_in[0];  // [64][500][1024]
    const float* w    = (const float*)d_in[1];  // [1024][128]
    const float* beta = (const float*)d_in[2];  // [128]
    const float* bias = (const float*)d_in[3];  // [128]
    float* out = (float*)d_out;                 // [64][128] fp32

    char* ws = (char*)d_ws;
    __hip_bfloat16* wT = (__hip_bfloat16*)(ws);
    float* wtab     = (float*)(ws + OFF_WTAB);
    float* scale    = (float*)(ws + OFF_SCALE);
    float* partials = (float*)(ws + OFF_PART);

    prep_kernel<<<890, 256, 0, stream>>>(w, beta, wT, wtab, scale);
    gemm_kernel<<<B_ * TILES, 512, 0, stream>>>(x, wT, wtab, partials);
    finalize_kernel<<<(B_ * DOUT) / 256, 256, 0, stream>>>(partials, scale, bias, out);
}

// Round 5
// 36.866 us; speedup vs baseline: 2.9518x; 1.1095x over previous
//
#include <hip/hip_runtime.h>
#include <hip/hip_bf16.h>

// Problem constants
#define B_    64
#define T_    500
#define DIN   1024
#define DOUT  128
#define EPSV  1e-8f
#define BM    128          // t-rows per block tile
#define BK    64           // k per LDS stage
#define NKC   2            // k-chunks (exact: weighting is linear in h)
#define KCL   (DIN / NKC)  // 512
#define NKT   (KCL / BK)   // 8 K-steps per block
#define TILES 4            // ceil(500/128)

typedef __attribute__((ext_vector_type(8))) short bf16x8;  // MFMA A/B frag
typedef __attribute__((ext_vector_type(4))) float f32x4;   // MFMA C/D frag

// Workspace layout (byte offsets)
//   wT    : bf16 [DOUT][DIN]                 @ 0        (262144 B)
//   wtab  : f32  [T_][DOUT]                  @ 262144   (256000 B)  c[t][d]=1-beta[d]^(T-t)
//   scale : f32  [DOUT]                      @ 518144   (512 B)
//   part  : f32  [B_][TILES][2][NKC][DOUT]   @ 518656   (524288 B)
#define OFF_WTAB  262144
#define OFF_SCALE 518144
#define OFF_PART  518656

__device__ inline short f2bf(float f) {
    __hip_bfloat16 h = __float2bfloat16(f);
    return __builtin_bit_cast(short, h);
}

// ---------------- prep: transpose/convert w, norm->scale, weight table ----------------
__global__ __launch_bounds__(256) void prep_kernel(
    const float* __restrict__ w, const float* __restrict__ beta,
    __hip_bfloat16* __restrict__ wT, float* __restrict__ wtab,
    float* __restrict__ scale)
{
    int bid = blockIdx.x, tid = threadIdx.x;
    if (bid < 512) {
        int i = bid * 256 + tid;
        int d = i >> 10, k = i & 1023;
        wT[(size_t)d * DIN + k] = __float2bfloat16(w[(size_t)k * DOUT + d]);
    } else if (bid < 640) {
        int d = bid - 512;
        __shared__ float red[256];
        float s = 0.f;
        for (int c = tid; c < DIN; c += 256) {
            float v = w[(size_t)c * DOUT + d];
            s += v * v;
        }
        red[tid] = s;
        __syncthreads();
        for (int off = 128; off > 0; off >>= 1) {
            if (tid < off) red[tid] += red[tid + off];
            __syncthreads();
        }
        if (tid == 0) scale[d] = 1.f / ((red[0] + EPSV) * (float)T_);
    } else {
        int i = (bid - 640) * 256 + tid;
        if (i < T_ * DOUT) {
            int t = i >> 7, d = i & 127;
            wtab[i] = 1.f - powf(beta[d], (float)(T_ - t));
        }
    }
}

// ---------------- main: LDS-staged GEMM + fused weighted time-reduction ----------------
// 512 blocks = 64 b x 4 t-tiles x 2 k-chunks; 512 threads = 8 waves (2 wr x 4 wc).
// Wave owns 64 rows x 32 cols over K=512. LDS double-buffered A/B [128][64]bf16,
// XOR-swizzled (byte ^= (row&7)<<4). 2 blocks/CU -> 4 waves/SIMD for latency hiding.
__global__ __launch_bounds__(512, 4) void gemm_kernel(
    const float* __restrict__ x, const __hip_bfloat16* __restrict__ wT,
    const float* __restrict__ wtab, float* __restrict__ partials)
{
    __shared__ __align__(16) char smem[2 * 32768];  // per buf: A @0 (16KB), B @16KB

    const int wg   = blockIdx.x;
    const int kc   = wg & 1;
    const int tile = (wg >> 1) & 3;
    const int b    = wg >> 3;
    const int t0   = tile * BM;
    const int kbase = kc * KCL;
    const int tid  = threadIdx.x;
    const int wid  = tid >> 6;
    const int lane = tid & 63;
    const int arow = lane & 15;
    const int kblk = lane >> 4;
    const int wr   = wid >> 2;   // 0..1  (row group of 64)
    const int wc   = wid & 3;    // 0..3  (col group of 32)

    const float* xb = x + (size_t)b * T_ * DIN + kbase;

    // ---- staging geometry (loop-invariant) ----
    // A: 4 passes; pass p covers rows p*32..p*32+31; 16 threads x float4 per row.
    const int sr = tid >> 4;     // 0..31 (row within pass)
    const int sc = tid & 15;     // float4 index within row
    const float* ag[4];
    int awoff[4];
#pragma unroll
    for (int p = 0; p < 4; ++p) {
        int row  = p * 32 + sr;
        int trow = t0 + row; if (trow >= T_) trow = T_ - 1;  // clamp; weight=0 kills it
        ag[p] = xb + (size_t)trow * DIN + sc * 4;
        awoff[p] = (row * 128 + sc * 8) ^ ((row & 7) << 4);
    }
    // B: col = tid>>2 (0..127); 2 chunks of 16B per thread
    const int bcol = tid >> 2;
    const int bch0 = (tid & 3) * 2;
    const __hip_bfloat16* bg0 = wT + (size_t)bcol * DIN + kbase + bch0 * 8;
    const __hip_bfloat16* bg1 = bg0 + 8;
    const int bwoff0 = (bcol * 128 + bch0 * 16)        ^ ((bcol & 7) << 4);
    const int bwoff1 = (bcol * 128 + (bch0 + 1) * 16)  ^ ((bcol & 7) << 4);

    // fragment read offsets (within A/B region), loop-invariant
    int aro[4][2], bro[2][2];
#pragma unroll
    for (int fm = 0; fm < 4; ++fm)
#pragma unroll
        for (int kk = 0; kk < 2; ++kk) {
            int row = wr * 64 + fm * 16 + arow;
            aro[fm][kk] = (row * 128 + kk * 64 + kblk * 16) ^ ((row & 7) << 4);
        }
#pragma unroll
    for (int fn = 0; fn < 2; ++fn)
#pragma unroll
        for (int kk = 0; kk < 2; ++kk) {
            int col = wc * 32 + fn * 16 + arow;
            bro[fn][kk] = (col * 128 + kk * 64 + kblk * 16) ^ ((col & 7) << 4);
        }

    f32x4 acc[4][2] = {};

    // ---- prologue: stage kt=0 into buf 0 ----
    {
        char* Ab = smem;
        char* Bb = smem + 16384;
#pragma unroll
        for (int p = 0; p < 4; ++p) {
            float4 v = *reinterpret_cast<const float4*>(ag[p]);
            short4 h; h.x = f2bf(v.x); h.y = f2bf(v.y); h.z = f2bf(v.z); h.w = f2bf(v.w);
            *reinterpret_cast<short4*>(Ab + awoff[p]) = h;
        }
        *reinterpret_cast<bf16x8*>(Bb + bwoff0) = *reinterpret_cast<const bf16x8*>(bg0);
        *reinterpret_cast<bf16x8*>(Bb + bwoff1) = *reinterpret_cast<const bf16x8*>(bg1);
    }
    __syncthreads();

    // ---- main loop: issue next-tile global loads early, compute current, write late ----
    for (int kt = 0; kt < NKT; ++kt) {
        const int cur = kt & 1;
        char* Acur = smem + cur * 32768;
        char* Bcur = Acur + 16384;
        char* Anxt = smem + (cur ^ 1) * 32768;
        char* Bnxt = Anxt + 16384;

        float4 av[4]; bf16x8 bv0, bv1;
        if (kt < NKT - 1) {
            const int kb = (kt + 1) * BK;
#pragma unroll
            for (int p = 0; p < 4; ++p)
                av[p] = *reinterpret_cast<const float4*>(ag[p] + kb);
            bv0 = *reinterpret_cast<const bf16x8*>(bg0 + kb);
            bv1 = *reinterpret_cast<const bf16x8*>(bg1 + kb);
        }

        // per-kk fragment loads keep the live register set small (<=128 for 4 w/SIMD)
#pragma unroll
        for (int kk = 0; kk < 2; ++kk) {
            bf16x8 bf0 = *reinterpret_cast<const bf16x8*>(Bcur + bro[0][kk]);
            bf16x8 bf1 = *reinterpret_cast<const bf16x8*>(Bcur + bro[1][kk]);
#pragma unroll
            for (int fm = 0; fm < 4; ++fm) {
                bf16x8 af = *reinterpret_cast<const bf16x8*>(Acur + aro[fm][kk]);
                acc[fm][0] = __builtin_amdgcn_mfma_f32_16x16x32_bf16(af, bf0, acc[fm][0], 0, 0, 0);
                acc[fm][1] = __builtin_amdgcn_mfma_f32_16x16x32_bf16(af, bf1, acc[fm][1], 0, 0, 0);
            }
        }

        if (kt < NKT - 1) {
#pragma unroll
            for (int p = 0; p < 4; ++p) {
                short4 h; h.x = f2bf(av[p].x); h.y = f2bf(av[p].y);
                h.z = f2bf(av[p].z); h.w = f2bf(av[p].w);
                *reinterpret_cast<short4*>(Anxt + awoff[p]) = h;
            }
            *reinterpret_cast<bf16x8*>(Bnxt + bwoff0) = bv0;
            *reinterpret_cast<bf16x8*>(Bnxt + bwoff1) = bv1;
        }
        __syncthreads();
    }

    // ---- epilogue: weighted reduction over rows within the wave's 64-row strip ----
    // C frag: col = lane&15, row = (lane>>4)*4 + r  [verified mapping]
    const int col0 = wc * 32 + arow;
    const int col1 = col0 + 16;
    float s0 = 0.f, s1 = 0.f;
#pragma unroll
    for (int fm = 0; fm < 4; ++fm) {
#pragma unroll
        for (int r = 0; r < 4; ++r) {
            int t = t0 + wr * 64 + fm * 16 + kblk * 4 + r;
            if (t < T_) {
                s0 += wtab[t * DOUT + col0] * acc[fm][0][r];
                s1 += wtab[t * DOUT + col1] * acc[fm][1][r];
            }
        }
    }
    s0 += __shfl_xor(s0, 16); s0 += __shfl_xor(s0, 32);
    s1 += __shfl_xor(s1, 16); s1 += __shfl_xor(s1, 32);

    if (kblk == 0) {
        float* p = partials + ((((size_t)b * TILES + tile) * 2 + wr) * NKC + kc) * DOUT;
        p[col0] = s0;
        p[col1] = s1;
    }
}

// ---------------- finalize: sum partials, scale, bias ----------------
__global__ __launch_bounds__(256) void finalize_kernel(
    const float* __restrict__ partials, const float* __restrict__ scale,
    const float* __restrict__ bias, float* __restrict__ out)
{
    int i = blockIdx.x * 256 + threadIdx.x;  // 8192 = B_*DOUT
    int b = i >> 7, d = i & 127;
    float s = 0.f;
#pragma unroll
    for (int p = 0; p < TILES * 2 * NKC; ++p)
        s += partials[((size_t)b * TILES * 2 * NKC + p) * DOUT + d];
    out[i] = s * scale[d] - bias[d];
}

extern "C" void kernel_launch(void* const* d_in, const int* in_sizes, int n_in,
                              void* d_out, int out_size, void* d_ws, size_t ws_size,
                              hipStream_t stream) {
    const float* x    = (const float*)d_in[0];  // [64][500][1024]
    const float* w    = (const float*)d_in[1];  // [1024][128]
    const float* beta = (const float*)d_in[2];  // [128]
    const float* bias = (const float*)d_in[3];  // [128]
    float* out = (float*)d_out;                 // [64][128] fp32

    char* ws = (char*)d_ws;
    __hip_bfloat16* wT = (__hip_bfloat16*)(ws);
    float* wtab     = (float*)(ws + OFF_WTAB);
    float* scale    = (float*)(ws + OFF_SCALE);
    float* partials = (float*)(ws + OFF_PART);

    prep_kernel<<<890, 256, 0, stream>>>(w, beta, wT, wtab, scale);
    gemm_kernel<<<B_ * TILES * NKC, 512, 0, stream>>>(x, wT, wtab, partials);
    finalize_kernel<<<(B_ * DOUT) / 256, 256, 0, stream>>>(partials, scale, bias, out);
}

// Round 6
// 34.660 us; speedup vs baseline: 3.1397x; 1.0637x over previous
//
#include <hip/hip_runtime.h>
#include <hip/hip_bf16.h>

// Problem constants
#define B_    64
#define T_    500
#define DIN   1024
#define DOUT  128
#define EPSV  1e-8f
#define BM    128          // t-rows per block tile
#define BK    64           // k per LDS stage
#define NKC   2            // k-chunks (exact: weighting is linear in h)
#define KCL   (DIN / NKC)  // 512
#define NKT   (KCL / BK)   // 8 K-steps per block
#define TILES 4            // ceil(500/128)

typedef __attribute__((ext_vector_type(8))) short bf16x8;  // MFMA A/B frag
typedef __attribute__((ext_vector_type(4))) float f32x4;   // MFMA C/D frag

// Workspace layout (byte offsets)
//   wT    : bf16 [DOUT][DIN]                 @ 0        (262144 B)
//   wtab  : f32  [T_][DOUT]                  @ 262144   (256000 B)  c[t][d]=1-beta[d]^(T-t)
//   scale : f32  [DOUT]                      @ 518144   (512 B)
//   part  : f32  [B_][TILES][2][NKC][DOUT]   @ 518656   (524288 B)
#define OFF_WTAB  262144
#define OFF_SCALE 518144
#define OFF_PART  518656

__device__ inline short f2bf(float f) {
    __hip_bfloat16 h = __float2bfloat16(f);
    return __builtin_bit_cast(short, h);
}

// Raw barrier: LDS-drain only. Global loads (to registers) ride across it with
// compiler-emitted COUNTED vmcnt at their consumer — avoids __syncthreads()'s
// unconditional vmcnt(0) drain (the m97 ~20% stall).
__device__ inline void block_sync_lds() {
    asm volatile("s_waitcnt lgkmcnt(0)" ::: "memory");
    __builtin_amdgcn_s_barrier();
    asm volatile("" ::: "memory");
}

// ---------------- prep: transpose/convert w, norm->scale, weight table ----------------
__global__ __launch_bounds__(256) void prep_kernel(
    const float* __restrict__ w, const float* __restrict__ beta,
    __hip_bfloat16* __restrict__ wT, float* __restrict__ wtab,
    float* __restrict__ scale)
{
    int bid = blockIdx.x, tid = threadIdx.x;
    if (bid < 512) {
        int i = bid * 256 + tid;
        int d = i >> 10, k = i & 1023;
        wT[(size_t)d * DIN + k] = __float2bfloat16(w[(size_t)k * DOUT + d]);
    } else if (bid < 640) {
        int d = bid - 512;
        __shared__ float red[256];
        float s = 0.f;
        for (int c = tid; c < DIN; c += 256) {
            float v = w[(size_t)c * DOUT + d];
            s += v * v;
        }
        red[tid] = s;
        __syncthreads();
        for (int off = 128; off > 0; off >>= 1) {
            if (tid < off) red[tid] += red[tid + off];
            __syncthreads();
        }
        if (tid == 0) scale[d] = 1.f / ((red[0] + EPSV) * (float)T_);
    } else {
        int i = (bid - 640) * 256 + tid;
        if (i < T_ * DOUT) {
            int t = i >> 7, d = i & 127;
            wtab[i] = 1.f - powf(beta[d], (float)(T_ - t));
        }
    }
}

// ---------------- main: LDS-staged GEMM + fused weighted time-reduction ----------------
// 512 blocks = 64 b x 4 t-tiles x 2 k-chunks; 512 threads = 8 waves (2 wr x 4 wc).
// LDS double-buffered A/B [128][64]bf16, XOR-swizzled. 2 blocks/CU.
// Software pipeline (2 K-steps ahead, register-queued):
//   step k: issue loads(k+2) -> compute LDS[k&1] -> cvt+write loads(k+1) -> raw barrier
__global__ __launch_bounds__(512, 4) void gemm_kernel(
    const float* __restrict__ x, const __hip_bfloat16* __restrict__ wT,
    const float* __restrict__ wtab, float* __restrict__ partials)
{
    __shared__ __align__(16) char smem[2 * 32768];  // per buf: A @0 (16KB), B @16KB

    const int wg   = blockIdx.x;
    const int kc   = wg & 1;
    const int tile = (wg >> 1) & 3;
    const int b    = wg >> 3;
    const int t0   = tile * BM;
    const int kbase = kc * KCL;
    const int tid  = threadIdx.x;
    const int wid  = tid >> 6;
    const int lane = tid & 63;
    const int arow = lane & 15;
    const int kblk = lane >> 4;
    const int wr   = wid >> 2;   // 0..1  (row group of 64)
    const int wc   = wid & 3;    // 0..3  (col group of 32)

    const float* xb = x + (size_t)b * T_ * DIN + kbase;

    // ---- staging geometry (loop-invariant) ----
    const int sr = tid >> 4;     // 0..31 (row within pass)
    const int sc = tid & 15;     // float4 index within row
    const float* ag[4];
    int awoff[4];
#pragma unroll
    for (int p = 0; p < 4; ++p) {
        int row  = p * 32 + sr;
        int trow = t0 + row; if (trow >= T_) trow = T_ - 1;  // clamp; weight=0 kills it
        ag[p] = xb + (size_t)trow * DIN + sc * 4;
        awoff[p] = (row * 128 + sc * 8) ^ ((row & 7) << 4);
    }
    const int bcol = tid >> 2;
    const int bch0 = (tid & 3) * 2;
    const __hip_bfloat16* bg0 = wT + (size_t)bcol * DIN + kbase + bch0 * 8;
    const __hip_bfloat16* bg1 = bg0 + 8;
    const int bwoff0 = (bcol * 128 + bch0 * 16)        ^ ((bcol & 7) << 4);
    const int bwoff1 = (bcol * 128 + (bch0 + 1) * 16)  ^ ((bcol & 7) << 4);

    // fragment read offsets, loop-invariant
    int aro[4][2], bro[2][2];
#pragma unroll
    for (int fm = 0; fm < 4; ++fm)
#pragma unroll
        for (int kk = 0; kk < 2; ++kk) {
            int row = wr * 64 + fm * 16 + arow;
            aro[fm][kk] = (row * 128 + kk * 64 + kblk * 16) ^ ((row & 7) << 4);
        }
#pragma unroll
    for (int fn = 0; fn < 2; ++fn)
#pragma unroll
        for (int kk = 0; kk < 2; ++kk) {
            int col = wc * 32 + fn * 16 + arow;
            bro[fn][kk] = (col * 128 + kk * 64 + kblk * 16) ^ ((col & 7) << 4);
        }

    f32x4 acc[4][2] = {};

    // ---- register-queued pipeline macros (all names static; rule #20) ----
#define DECL_SET(S) float4 S##a0, S##a1, S##a2, S##a3; bf16x8 S##b0, S##b1;
#define LOAD_SET(S, KB) \
    S##a0 = *reinterpret_cast<const float4*>(ag[0] + (KB)); \
    S##a1 = *reinterpret_cast<const float4*>(ag[1] + (KB)); \
    S##a2 = *reinterpret_cast<const float4*>(ag[2] + (KB)); \
    S##a3 = *reinterpret_cast<const float4*>(ag[3] + (KB)); \
    S##b0 = *reinterpret_cast<const bf16x8*>(bg0 + (KB));   \
    S##b1 = *reinterpret_cast<const bf16x8*>(bg1 + (KB));
#define WRITE_SET(S, AB, BB) { \
    short4 h0; h0.x=f2bf(S##a0.x); h0.y=f2bf(S##a0.y); h0.z=f2bf(S##a0.z); h0.w=f2bf(S##a0.w); \
    *reinterpret_cast<short4*>((AB) + awoff[0]) = h0; \
    short4 h1; h1.x=f2bf(S##a1.x); h1.y=f2bf(S##a1.y); h1.z=f2bf(S##a1.z); h1.w=f2bf(S##a1.w); \
    *reinterpret_cast<short4*>((AB) + awoff[1]) = h1; \
    short4 h2; h2.x=f2bf(S##a2.x); h2.y=f2bf(S##a2.y); h2.z=f2bf(S##a2.z); h2.w=f2bf(S##a2.w); \
    *reinterpret_cast<short4*>((AB) + awoff[2]) = h2; \
    short4 h3; h3.x=f2bf(S##a3.x); h3.y=f2bf(S##a3.y); h3.z=f2bf(S##a3.z); h3.w=f2bf(S##a3.w); \
    *reinterpret_cast<short4*>((AB) + awoff[3]) = h3; \
    *reinterpret_cast<bf16x8*>((BB) + bwoff0) = S##b0; \
    *reinterpret_cast<bf16x8*>((BB) + bwoff1) = S##b1; }
#define COMPUTE(AB, BB) { \
    _Pragma("unroll") \
    for (int kk = 0; kk < 2; ++kk) { \
        bf16x8 bf0 = *reinterpret_cast<const bf16x8*>((BB) + bro[0][kk]); \
        bf16x8 bf1 = *reinterpret_cast<const bf16x8*>((BB) + bro[1][kk]); \
        _Pragma("unroll") \
        for (int fm = 0; fm < 4; ++fm) { \
            bf16x8 af = *reinterpret_cast<const bf16x8*>((AB) + aro[fm][kk]); \
            acc[fm][0] = __builtin_amdgcn_mfma_f32_16x16x32_bf16(af, bf0, acc[fm][0], 0, 0, 0); \
            acc[fm][1] = __builtin_amdgcn_mfma_f32_16x16x32_bf16(af, bf1, acc[fm][1], 0, 0, 0); \
        } } }

    DECL_SET(qe_)   // even set
    DECL_SET(qo_)   // odd set

    // ---- prologue: load kt=0 and kt=1; write kt=0 -> LDS0 ----
    LOAD_SET(qe_, 0)
    LOAD_SET(qo_, BK)
    WRITE_SET(qe_, smem, smem + 16384)
    block_sync_lds();

    // ---- main loop, fully unrolled so set selection is static ----
#pragma unroll
    for (int kt = 0; kt < NKT; ++kt) {
        char* Acur = smem + (kt & 1) * 32768;
        char* Bcur = Acur + 16384;
        char* Anxt = smem + ((kt + 1) & 1) * 32768;
        char* Bnxt = Anxt + 16384;

        // issue loads for kt+2 into the set consumed at step kt-1
        if (kt + 2 < NKT) {
            if (kt & 1) { LOAD_SET(qo_, (kt + 2) * BK) }
            else        { LOAD_SET(qe_, (kt + 2) * BK) }
        }

        COMPUTE(Acur, Bcur)

        // convert+write the set for kt+1 (loaded at step kt-1 / prologue)
        if (kt + 1 < NKT) {
            if (kt & 1) { WRITE_SET(qe_, Anxt, Bnxt) }
            else        { WRITE_SET(qo_, Anxt, Bnxt) }
            block_sync_lds();
        }
    }
#undef DECL_SET
#undef LOAD_SET
#undef WRITE_SET
#undef COMPUTE

    // ---- epilogue: weighted reduction over rows within the wave's 64-row strip ----
    // C frag: col = lane&15, row = (lane>>4)*4 + r  [verified mapping]
    const int col0 = wc * 32 + arow;
    const int col1 = col0 + 16;
    float s0 = 0.f, s1 = 0.f;
#pragma unroll
    for (int fm = 0; fm < 4; ++fm) {
#pragma unroll
        for (int r = 0; r < 4; ++r) {
            int t = t0 + wr * 64 + fm * 16 + kblk * 4 + r;
            if (t < T_) {
                s0 += wtab[t * DOUT + col0] * acc[fm][0][r];
                s1 += wtab[t * DOUT + col1] * acc[fm][1][r];
            }
        }
    }
    s0 += __shfl_xor(s0, 16); s0 += __shfl_xor(s0, 32);
    s1 += __shfl_xor(s1, 16); s1 += __shfl_xor(s1, 32);

    if (kblk == 0) {
        float* p = partials + ((((size_t)b * TILES + tile) * 2 + wr) * NKC + kc) * DOUT;
        p[col0] = s0;
        p[col1] = s1;
    }
}

// ---------------- finalize: sum partials, scale, bias ----------------
__global__ __launch_bounds__(256) void finalize_kernel(
    const float* __restrict__ partials, const float* __restrict__ scale,
    const float* __restrict__ bias, float* __restrict__ out)
{
    int i = blockIdx.x * 256 + threadIdx.x;  // 8192 = B_*DOUT
    int b = i >> 7, d = i & 127;
    float s = 0.f;
#pragma unroll
    for (int p = 0; p < TILES * 2 * NKC; ++p)
        s += partials[((size_t)b * TILES * 2 * NKC + p) * DOUT + d];
    out[i] = s * scale[d] - bias[d];
}

extern "C" void kernel_launch(void* const* d_in, const int* in_sizes, int n_in,
                              void* d_out, int out_size, void* d_ws, size_t ws_size,
                              hipStream_t stream) {
    const float* x    = (const float*)d_in[0];  // [64][500][1024]
    const float* w    = (const float*)d_in[1];  // [1024][128]
    const float* beta = (const float*)d_in[2];  // [128]
    const float* bias = (const float*)d_in[3];  // [128]
    float* out = (float*)d_out;                 // [64][128] fp32

    char* ws = (char*)d_ws;
    __hip_bfloat16* wT = (__hip_bfloat16*)(ws);
    float* wtab     = (float*)(ws + OFF_WTAB);
    float* scale    = (float*)(ws + OFF_SCALE);
    float* partials = (float*)(ws + OFF_PART);

    prep_kernel<<<890, 256, 0, stream>>>(w, beta, wT, wtab, scale);
    gemm_kernel<<<B_ * TILES * NKC, 512, 0, stream>>>(x, wT, wtab, partials);
    finalize_kernel<<<(B_ * DOUT) / 256, 256, 0, stream>>>(partials, scale, bias, out);
}